// Round 6
// baseline (261.958 us; speedup 1.0000x reference)
//
#include <hip/hip_runtime.h>
#include <cstdint>
#include <cstddef>

// ALiBi MHA, MI355X/gfx950. fp16 MFMA (16x16x32) pipeline.
// R6 changes vs R5:
//  - flash: PIPELINED single-barrier K-loop with K/V double-buffer (prefetch
//    tile i+1 during compute of tile i; one fused waitcnt+barrier per iter).
//  - ALiBi skip threshold 30 -> 22 (error bound ~2e-4 abs, margin 7e-3).
//  - GEMMs: BK=64 (16 barrier-drains per block instead of 32).
//  - gemm_out: split-K=2 (512 blocks = 2/CU) + fp32 atomicAdd epilogue,
//    d_out zeroed via hipMemsetAsync.

typedef unsigned short u16;
typedef __attribute__((ext_vector_type(8))) _Float16 half8;
typedef __attribute__((ext_vector_type(8))) unsigned short u16x8;
typedef __attribute__((ext_vector_type(4))) float f32x4;

#define DEVI static __device__ __forceinline__
#define MFMA16(a, b, c) __builtin_amdgcn_mfma_f32_16x16x32_f16(a, b, c, 0, 0, 0)

DEVI u16 f2h_bits(float f) {
  _Float16 h = (_Float16)f;  // v_cvt_f16_f32, RNE
  union { _Float16 h; u16 u; } v; v.h = h;
  return v.u;
}

// async global->LDS, 16B per lane. LDS dest must be wave-uniform base + lane*16.
DEVI void gl_lds16(const u16* g, u16* l) {
  __builtin_amdgcn_global_load_lds(
      (const __attribute__((address_space(1))) void*)g,
      (__attribute__((address_space(3))) void*)l, 16, 0, 0);
}

// ---------------- cast fp32 -> fp16 bits, 4 elems/thread, z selects tensor ----------------
__global__ __launch_bounds__(256) void cast3_h(const float* __restrict__ in0,
                                               const float* __restrict__ in1,
                                               const float* __restrict__ in2,
                                               u16* __restrict__ o0,
                                               u16* __restrict__ o1,
                                               u16* __restrict__ o2, int n) {
  const float* in = blockIdx.z == 0 ? in0 : (blockIdx.z == 1 ? in1 : in2);
  u16* out = blockIdx.z == 0 ? o0 : (blockIdx.z == 1 ? o1 : o2);
  int i = (blockIdx.x * 256 + threadIdx.x) * 4;
  if (i + 3 < n) {
    const float4 v = *(const float4*)(in + i);
    ushort4 o;
    o.x = f2h_bits(v.x); o.y = f2h_bits(v.y); o.z = f2h_bits(v.z); o.w = f2h_bits(v.w);
    *(ushort4*)(out + i) = o;
  }
}

// ---------------- Wt[n][k] = (f16)W[k][n], 1024x1024, LDS-tiled, z selects W ----------------
__global__ __launch_bounds__(256) void transpose4_h(
    const float* __restrict__ W0, const float* __restrict__ W1,
    const float* __restrict__ W2, const float* __restrict__ W3,
    u16* __restrict__ T0, u16* __restrict__ T1, u16* __restrict__ T2,
    u16* __restrict__ T3) {
  const float* W = blockIdx.z == 0 ? W0 : (blockIdx.z == 1 ? W1 : (blockIdx.z == 2 ? W2 : W3));
  u16* Wt = blockIdx.z == 0 ? T0 : (blockIdx.z == 1 ? T1 : (blockIdx.z == 2 ? T2 : T3));
  __shared__ float tile[32][33];
  const int bx = blockIdx.x * 32;
  const int by = blockIdx.y * 32;
  const int x = threadIdx.x & 31;
  const int y0 = threadIdx.x >> 5;  // 0..7
#pragma unroll
  for (int i = y0; i < 32; i += 8)
    tile[i][x] = W[(size_t)(by + i) * 1024 + bx + x];
  __syncthreads();
#pragma unroll
  for (int i = y0; i < 32; i += 8)
    Wt[(size_t)(bx + i) * 1024 + by + x] = f2h_bits(tile[x][i]);
}

// ---- Vt[(b*16+h)*64+d][s] = Vp[b*2048+s][h*64+d], via 64x64 LDS tile ----
__global__ __launch_bounds__(256) void vtrans(const u16* __restrict__ Vp,
                                              u16* __restrict__ Vt) {
  __shared__ u16 tile[64][72];  // +8 pad breaks transpose-read bank alignment
  const int t = threadIdx.x;
  const int s0 = blockIdx.x * 64;
  const int bh = blockIdx.y;            // b*16 + h
  const int b = bh >> 4, h = bh & 15;
#pragma unroll
  for (int it = 0; it < 2; ++it) {
    const int ci = it * 256 + t;
    const int srow = ci >> 3, cc = (ci & 7) << 3;
    const u16x8 v = *(const u16x8*)(Vp + (size_t)(b * 2048 + s0 + srow) * 1024 + h * 64 + cc);
    *(u16x8*)(&tile[srow][cc]) = v;
  }
  __syncthreads();
#pragma unroll
  for (int it = 0; it < 2; ++it) {
    const int ci = it * 256 + t;
    const int drow = ci >> 3, cc = (ci & 7) << 3;
    u16x8 o;
#pragma unroll
    for (int j = 0; j < 8; ++j) o[j] = tile[cc + j][drow];
    *(u16x8*)(Vt + ((size_t)bh * 64 + drow) * 2048 + s0 + cc) = o;
  }
}

// ---------------- GEMM body, BK=64: C[128x128] tile of A[M][1024] x Bt[1024][1024]^T ----
// 64-elem LDS rows = 8 chunks of 8; staging-side chunk XOR (c ^ row&7) kills the
// 16-way frag-read conflict of the 128B row stride.
// mode 0: fp32 store; mode 1: f16 store; mode 3: fp32 atomicAdd (split-K)
DEVI void gemm_body(const u16* __restrict__ A, const u16* __restrict__ Bt,
                    void* __restrict__ Cout, int mode, int kLo, int kHi,
                    u16* As, u16* Bs) {
  constexpr int K = 1024, N = 1024;
  const int t = threadIdx.x;
  const int lane = t & 63;
  const int quad = lane >> 4;
  const int l16 = lane & 15;
  const int wid = t >> 6;
  const int mBase = blockIdx.y * 128;
  const int nBase = blockIdx.x * 128;
  const int wM = (wid >> 1) * 64;
  const int wN = (wid & 1) * 64;
  const int cswz = l16 & 7;  // frag-read chunk xor

  f32x4 acc[4][4];
#pragma unroll
  for (int i = 0; i < 4; ++i)
#pragma unroll
    for (int j = 0; j < 4; ++j) acc[i][j] = (f32x4){0.f, 0.f, 0.f, 0.f};

  for (int kt = kLo; kt < kHi; ++kt) {
    const int kB = kt * 64;
    __syncthreads();  // protect LDS reuse from previous iteration's reads
#pragma unroll
    for (int i = 0; i < 4; ++i) {  // each tile 128x64 f16 = 1024 chunks / 256 thr
      const int ci = i * 256 + t;
      const int row = ci >> 3;                       // 8 chunks per 64-elem row
      const int col = (((ci & 7) ^ (row & 7)) << 3); // staging-side swizzle
      gl_lds16(A + (size_t)(mBase + row) * K + kB + col, As + ci * 8);
      gl_lds16(Bt + (size_t)(nBase + row) * K + kB + col, Bs + ci * 8);
    }
    __syncthreads();  // barrier drains vmcnt

#pragma unroll
    for (int kk = 0; kk < 2; ++kk) {
      const int ck = (((kk * 4 + quad) ^ cswz) << 3);
      half8 a[4], b[4];
#pragma unroll
      for (int mi = 0; mi < 4; ++mi)
        a[mi] = *(const half8*)(As + (wM + mi * 16 + l16) * 64 + ck);
#pragma unroll
      for (int ni = 0; ni < 4; ++ni)
        b[ni] = *(const half8*)(Bs + (wN + ni * 16 + l16) * 64 + ck);
#pragma unroll
      for (int mi = 0; mi < 4; ++mi)
#pragma unroll
        for (int ni = 0; ni < 4; ++ni)
          acc[mi][ni] = MFMA16(a[mi], b[ni], acc[mi][ni]);
    }
  }

  // epilogue. C/D layout: row = quad*4 + reg, col = lane&15 (m89/m91-verified)
#pragma unroll
  for (int mi = 0; mi < 4; ++mi) {
#pragma unroll
    for (int ni = 0; ni < 4; ++ni) {
#pragma unroll
      for (int r = 0; r < 4; ++r) {
        const int m = mBase + wM + mi * 16 + quad * 4 + r;
        const int n = nBase + wN + ni * 16 + l16;
        const float v = acc[mi][ni][r];
        if (mode == 0) {
          ((float*)Cout)[(size_t)m * N + n] = v;
        } else if (mode == 1) {
          ((u16*)Cout)[(size_t)m * N + n] = f2h_bits(v);
        } else {
          atomicAdd((float*)Cout + (size_t)m * N + n, v);
        }
      }
    }
  }
}

__global__ __launch_bounds__(256) void proj_qkv(
    const u16* __restrict__ qb, const u16* __restrict__ kb, const u16* __restrict__ vb,
    const u16* __restrict__ Wqt, const u16* __restrict__ Wkt, const u16* __restrict__ Wvt,
    u16* __restrict__ Qp, u16* __restrict__ Kp, u16* __restrict__ Vp) {
  __shared__ u16 As[128 * 64];
  __shared__ u16 Bs[128 * 64];
  const int z = blockIdx.z;
  const u16* A = z == 0 ? qb : (z == 1 ? kb : vb);
  const u16* Bt = z == 0 ? Wqt : (z == 1 ? Wkt : Wvt);
  void* C = z == 0 ? (void*)Qp : (z == 1 ? (void*)Kp : (void*)Vp);
  gemm_body(A, Bt, C, 1, 0, 16, As, Bs);
}

// split-K=2: grid (8,32,2); z picks K-half; accumulate into pre-zeroed d_out
__global__ __launch_bounds__(256) void gemm_out(const u16* __restrict__ Ao,
                                                const u16* __restrict__ Wot,
                                                float* __restrict__ out) {
  __shared__ u16 As[128 * 64];
  __shared__ u16 Bs[128 * 64];
  const int z = blockIdx.z;
  gemm_body(Ao, Wot, out, 3, z * 8, z * 8 + 8, As, Bs);
}

// ---------------- flash attention + ALiBi, no-max exp2 softmax, pipelined ----------------
// 1D grid 1024 = LPT order (h=15 first). 128 thr = 2 waves x 32 q-rows, K-tile 64.
// K/V double-buffered: prefetch tile i+1 issued right after the iteration
// barrier, compute on tile i covers its latency; ONE fused waitcnt+barrier/iter.
// ALiBi skip: tile dropped when sl2*dist > 22 (neglected mass < ~2^-13 of l).
__global__ __launch_bounds__(128, 2) void flash_alibi(
    const u16* __restrict__ Qg, const u16* __restrict__ Kg,
    const u16* __restrict__ Vtg, u16* __restrict__ Og) {
  constexpr int S = 2048, Dm = 1024, HD = 64;
  __shared__ u16 Qs[64 * 64];       // 8 KB
  __shared__ u16 Ks[2][64 * 64];    // 16 KB dbuf
  __shared__ u16 Vs[2][64 * 64];    // 16 KB dbuf  Vs[d][k]
  __shared__ u16 Ps[64 * 64];       // 8 KB  col-swizzled       (48 KB total)
  const int t = threadIdx.x, lane = t & 63, wid = t >> 6;  // wid 0..1
  const int quad = lane >> 4, l16 = lane & 15;
  const int idx = blockIdx.x;
  const int h = 15 - (idx >> 6);       // LPT: longest heads dispatched first
  const int qt = (idx >> 1) & 31;
  const int b = idx & 1;
  const int qBase = qt * 64;
  const size_t qRow0 = (size_t)b * S + qBase;
  const float sl2 = __builtin_amdgcn_exp2f(-0.5f * (float)(h + 1)) * 1.44269504f;
  const float sc2 = 0.125f * 1.44269504f;  // (1/sqrt(64))*log2(e)
  const int Di = (int)(22.0f / sl2);
  const int ktLo = max(0, (qBase - Di) >> 6);
  const int ktHi = min(31, (qBase + 63 + Di) >> 6);
  const int cswz = ((l16 & 7) << 3);  // frag-read chunk xor (x8 elems)
  const u16* Kgb = Kg + (size_t)b * S * Dm + h * HD;
  const u16* Vgb = Vtg + (size_t)(b * 16 + h) * HD * S;

  // stage Q tile once: 64 rows x 8 chunks = 512 chunks / 128 thr
#pragma unroll
  for (int i = 0; i < 4; ++i) {
    const int ci = i * 128 + t;
    const int row = ci >> 3, col = (((ci & 7) ^ (row & 7)) << 3);
    gl_lds16(Qg + (qRow0 + row) * Dm + h * HD + col, Qs + ci * 8);
  }
  // stage K/V of first tile into buffer 0
#pragma unroll
  for (int i = 0; i < 4; ++i) {
    const int ci = i * 128 + t;
    const int row = ci >> 3, col = (((ci & 7) ^ (row & 7)) << 3);
    gl_lds16(Kgb + (size_t)(ktLo * 64 + row) * Dm + col, Ks[0] + ci * 8);
    gl_lds16(Vgb + (size_t)row * S + ktLo * 64 + col, Vs[0] + ci * 8);
  }

  // ALiBi row bias (constant over kt): bi[m][r] = sl2 * global_q_row
  float bi[2][4];
#pragma unroll
  for (int m = 0; m < 2; ++m)
#pragma unroll
    for (int r = 0; r < 4; ++r)
      bi[m][r] = sl2 * (float)(qBase + wid * 32 + m * 16 + quad * 4 + r);

  f32x4 acc_o[2][4];
#pragma unroll
  for (int m = 0; m < 2; ++m)
#pragma unroll
    for (int nd = 0; nd < 4; ++nd) acc_o[m][nd] = (f32x4){0.f, 0.f, 0.f, 0.f};
  float lrow[2][4] = {{0.f, 0.f, 0.f, 0.f}, {0.f, 0.f, 0.f, 0.f}};

  const int pRowBase = wid * 32;  // this wave's private 32-row P region
  int cur = 0;

  for (int kt = ktLo; kt <= ktHi; ++kt, cur ^= 1) {
    // fused drain+barrier: all waves' staging for buf[cur] (and Q, iter 0) done;
    // also orders prior-iter LDS reads of buf[cur^1] before its overwrite below.
    __asm__ volatile("s_waitcnt vmcnt(0) lgkmcnt(0)\n\ts_barrier" ::: "memory");

    // prefetch next K/V tile into the other buffer; compute below covers it
    if (kt < ktHi) {
      const int kB2 = (kt + 1) * 64;
      u16* Kd = Ks[cur ^ 1];
      u16* Vd = Vs[cur ^ 1];
#pragma unroll
      for (int i = 0; i < 4; ++i) {
        const int ci = i * 128 + t;
        const int row = ci >> 3, col = (((ci & 7) ^ (row & 7)) << 3);
        gl_lds16(Kgb + (size_t)(kB2 + row) * Dm + col, Kd + ci * 8);
        gl_lds16(Vgb + (size_t)row * S + kB2 + col, Vd + ci * 8);
      }
    }

    const int kB = kt * 64;
    // S = Q K^T : per wave 32q x 64k
    f32x4 s[2][4];
#pragma unroll
    for (int m = 0; m < 2; ++m)
#pragma unroll
      for (int ni = 0; ni < 4; ++ni) s[m][ni] = (f32x4){0.f, 0.f, 0.f, 0.f};
#pragma unroll
    for (int ks = 0; ks < 2; ++ks) {
      const int ck = ((ks * 4 + quad) << 3) ^ cswz;
      const half8 a0 = *(const half8*)(Qs + (wid * 32 + l16) * HD + ck);
      const half8 a1 = *(const half8*)(Qs + (wid * 32 + 16 + l16) * HD + ck);
#pragma unroll
      for (int ni = 0; ni < 4; ++ni) {
        const half8 bk = *(const half8*)(Ks[cur] + (ni * 16 + l16) * HD + ck);
        s[0][ni] = MFMA16(a0, bk, s[0][ni]);
        s[1][ni] = MFMA16(a1, bk, s[1][ni]);
      }
    }

    // p = exp2(s*sc2 - |bi - bj|); per-lane l partials; write swizzled P
    float bj[4];
#pragma unroll
    for (int ni = 0; ni < 4; ++ni) bj[ni] = sl2 * (float)(kB + ni * 16 + l16);
#pragma unroll
    for (int m = 0; m < 2; ++m) {
#pragma unroll
      for (int r = 0; r < 4; ++r) {
        float rs = 0.f;
        const int prow = (pRowBase + m * 16 + quad * 4 + r) * 64;
#pragma unroll
        for (int ni = 0; ni < 4; ++ni) {
          const float d = fabsf(bi[m][r] - bj[ni]);
          const float p = __builtin_amdgcn_exp2f(s[m][ni][r] * sc2 - d);
          rs += p;
          Ps[prow + ((ni * 16 + l16) ^ (quad << 4))] = f2h_bits(p);
        }
        lrow[m][r] += rs;
      }
    }
    // P region is per-wave: wave-local LDS drain is sufficient (no block barrier)
    __asm__ volatile("s_waitcnt lgkmcnt(0)" ::: "memory");

    // O += P V : P A-frags (swizzled, 16B-contiguous), V B-frags
#pragma unroll
    for (int ks = 0; ks < 2; ++ks) {
      const int pk = (ks * 32 + quad * 8) ^ ((l16 & 12) << 2);
      const int ck = ((ks * 4 + quad) << 3) ^ cswz;
      const half8 aP0 = *(const half8*)(Ps + (pRowBase + l16) * 64 + pk);
      const half8 aP1 = *(const half8*)(Ps + (pRowBase + 16 + l16) * 64 + pk);
#pragma unroll
      for (int nd = 0; nd < 4; ++nd) {
        const half8 bv = *(const half8*)(Vs[cur] + (nd * 16 + l16) * HD + ck);
        acc_o[0][nd] = MFMA16(aP0, bv, acc_o[0][nd]);
        acc_o[1][nd] = MFMA16(aP1, bv, acc_o[1][nd]);
      }
    }
  }

  // epilogue: reduce l across the 16 lanes sharing each row, O /= l, write f16
#pragma unroll
  for (int m = 0; m < 2; ++m) {
#pragma unroll
    for (int r = 0; r < 4; ++r) {
      float l = lrow[m][r];
      l += __shfl_xor(l, 1);
      l += __shfl_xor(l, 2);
      l += __shfl_xor(l, 4);
      l += __shfl_xor(l, 8);
      const float inv = 1.f / l;
      const int rloc = wid * 32 + m * 16 + quad * 4 + r;
#pragma unroll
      for (int nd = 0; nd < 4; ++nd)
        Og[(qRow0 + rloc) * Dm + h * HD + nd * 16 + l16] = f2h_bits(acc_o[m][nd][r] * inv);
    }
  }
}

extern "C" void kernel_launch(void* const* d_in, const int* in_sizes, int n_in,
                              void* d_out, int out_size, void* d_ws, size_t ws_size,
                              hipStream_t stream) {
  const float* q  = (const float*)d_in[0];
  const float* k  = (const float*)d_in[1];
  const float* v  = (const float*)d_in[2];
  const float* Wq = (const float*)d_in[3];
  const float* Wk = (const float*)d_in[4];
  const float* Wv = (const float*)d_in[5];
  const float* Wo = (const float*)d_in[6];
  char* ws = (char*)d_ws;
  const size_t MB = 1ull << 20;
  // workspace map (64 MB total)
  u16* qb  = (u16*)(ws + 0 * MB);    // 8 MB  q fp16
  u16* kb  = (u16*)(ws + 8 * MB);    // 8 MB
  u16* vb  = (u16*)(ws + 16 * MB);   // 8 MB  (reused as Vt after proj consumes it)
  u16* Wqt = (u16*)(ws + 24 * MB);   // 2 MB  W^T fp16
  u16* Wkt = (u16*)(ws + 26 * MB);
  u16* Wvt = (u16*)(ws + 28 * MB);
  u16* Wot = (u16*)(ws + 30 * MB);
  u16* Qp  = (u16*)(ws + 32 * MB);   // 8 MB  Q proj [4096][1024]
  u16* Kp  = (u16*)(ws + 40 * MB);   // 8 MB
  u16* Vp  = (u16*)(ws + 48 * MB);   // 8 MB  V proj row-major [4096][1024]
  u16* Ao  = (u16*)(ws + 56 * MB);   // 8 MB  attention out [4096][1024]
  u16* Vt  = vb;                     // Vt[b][h][64][2048] overwrites vb (safe: proj done)

  const int n = 2 * 2048 * 1024;
  hipMemsetAsync(d_out, 0, (size_t)out_size * 4, stream);  // split-K accumulator
  cast3_h<<<dim3(n / 1024, 1, 3), 256, 0, stream>>>(q, k, v, qb, kb, vb, n);
  transpose4_h<<<dim3(32, 32, 4), 256, 0, stream>>>(Wq, Wk, Wv, Wo, Wqt, Wkt, Wvt, Wot);
  proj_qkv<<<dim3(8, 32, 3), 256, 0, stream>>>(qb, kb, vb, Wqt, Wkt, Wvt, Qp, Kp, Vp);
  vtrans<<<dim3(32, 32), 256, 0, stream>>>(Vp, Vt);
  flash_alibi<<<1024, 128, 0, stream>>>(Qp, Kp, Vt, Ao);
  gemm_out<<<dim3(8, 32, 2), 256, 0, stream>>>(Ao, Wot, (float*)d_out);
}

// Round 8
// 245.936 us; speedup vs baseline: 1.0651x; 1.0651x over previous
//
#include <hip/hip_runtime.h>
#include <cstdint>
#include <cstddef>

// ALiBi MHA, MI355X/gfx950. fp16 MFMA (16x16x32) pipeline.
// R8 = R7 with the add2 element-count bug fixed (was n/2 -> half of d_out
// never written; absmax = ref max).
//  - flash SPLIT-K: window segmented into <=8-tile chunks (h>=13: 4 segs,
//    h=12: 3, h=9..11: 2, else 1) -> 1920 blocks, critical path 32 -> <=9
//    iters, real backfill + LPT. Linear no-max softmax makes segments
//    directly summable: blocks write unnormalized fp16 O_part + fp32 l_part;
//    flash_merge sums/normalizes into Ao.
//  - gemm_out: split-K=2 into fp32 partial buffers + add2 kernel.

typedef unsigned short u16;
typedef __attribute__((ext_vector_type(8))) _Float16 half8;
typedef __attribute__((ext_vector_type(8))) unsigned short u16x8;
typedef __attribute__((ext_vector_type(4))) float f32x4;

#define DEVI static __device__ __forceinline__
#define MFMA16(a, b, c) __builtin_amdgcn_mfma_f32_16x16x32_f16(a, b, c, 0, 0, 0)

DEVI u16 f2h_bits(float f) {
  _Float16 h = (_Float16)f;  // v_cvt_f16_f32, RNE
  union { _Float16 h; u16 u; } v; v.h = h;
  return v.u;
}

// async global->LDS, 16B per lane. LDS dest must be wave-uniform base + lane*16.
DEVI void gl_lds16(const u16* g, u16* l) {
  __builtin_amdgcn_global_load_lds(
      (const __attribute__((address_space(1))) void*)g,
      (__attribute__((address_space(3))) void*)l, 16, 0, 0);
}

// ---------------- cast fp32 -> fp16 bits, 4 elems/thread, z selects tensor ----------------
__global__ __launch_bounds__(256) void cast3_h(const float* __restrict__ in0,
                                               const float* __restrict__ in1,
                                               const float* __restrict__ in2,
                                               u16* __restrict__ o0,
                                               u16* __restrict__ o1,
                                               u16* __restrict__ o2, int n) {
  const float* in = blockIdx.z == 0 ? in0 : (blockIdx.z == 1 ? in1 : in2);
  u16* out = blockIdx.z == 0 ? o0 : (blockIdx.z == 1 ? o1 : o2);
  int i = (blockIdx.x * 256 + threadIdx.x) * 4;
  if (i + 3 < n) {
    const float4 v = *(const float4*)(in + i);
    ushort4 o;
    o.x = f2h_bits(v.x); o.y = f2h_bits(v.y); o.z = f2h_bits(v.z); o.w = f2h_bits(v.w);
    *(ushort4*)(out + i) = o;
  }
}

// ---------------- Wt[n][k] = (f16)W[k][n], 1024x1024, LDS-tiled, z selects W ----------------
__global__ __launch_bounds__(256) void transpose4_h(
    const float* __restrict__ W0, const float* __restrict__ W1,
    const float* __restrict__ W2, const float* __restrict__ W3,
    u16* __restrict__ T0, u16* __restrict__ T1, u16* __restrict__ T2,
    u16* __restrict__ T3) {
  const float* W = blockIdx.z == 0 ? W0 : (blockIdx.z == 1 ? W1 : (blockIdx.z == 2 ? W2 : W3));
  u16* Wt = blockIdx.z == 0 ? T0 : (blockIdx.z == 1 ? T1 : (blockIdx.z == 2 ? T2 : T3));
  __shared__ float tile[32][33];
  const int bx = blockIdx.x * 32;
  const int by = blockIdx.y * 32;
  const int x = threadIdx.x & 31;
  const int y0 = threadIdx.x >> 5;  // 0..7
#pragma unroll
  for (int i = y0; i < 32; i += 8)
    tile[i][x] = W[(size_t)(by + i) * 1024 + bx + x];
  __syncthreads();
#pragma unroll
  for (int i = y0; i < 32; i += 8)
    Wt[(size_t)(bx + i) * 1024 + by + x] = f2h_bits(tile[x][i]);
}

// ---- Vt[(b*16+h)*64+d][s] = Vp[b*2048+s][h*64+d], via 64x64 LDS tile ----
__global__ __launch_bounds__(256) void vtrans(const u16* __restrict__ Vp,
                                              u16* __restrict__ Vt) {
  __shared__ u16 tile[64][72];  // +8 pad breaks transpose-read bank alignment
  const int t = threadIdx.x;
  const int s0 = blockIdx.x * 64;
  const int bh = blockIdx.y;            // b*16 + h
  const int b = bh >> 4, h = bh & 15;
#pragma unroll
  for (int it = 0; it < 2; ++it) {
    const int ci = it * 256 + t;
    const int srow = ci >> 3, cc = (ci & 7) << 3;
    const u16x8 v = *(const u16x8*)(Vp + (size_t)(b * 2048 + s0 + srow) * 1024 + h * 64 + cc);
    *(u16x8*)(&tile[srow][cc]) = v;
  }
  __syncthreads();
#pragma unroll
  for (int it = 0; it < 2; ++it) {
    const int ci = it * 256 + t;
    const int drow = ci >> 3, cc = (ci & 7) << 3;
    u16x8 o;
#pragma unroll
    for (int j = 0; j < 8; ++j) o[j] = tile[cc + j][drow];
    *(u16x8*)(Vt + ((size_t)bh * 64 + drow) * 2048 + s0 + cc) = o;
  }
}

// ---------------- GEMM body, BK=64: C[128x128] tile of A[M][1024] x Bt[1024][1024]^T ----
// 64-elem LDS rows = 8 chunks of 8; staging-side chunk XOR (c ^ row&7) kills the
// 16-way frag-read conflict of the 128B row stride. mode 0: fp32; mode 1: f16.
DEVI void gemm_body(const u16* __restrict__ A, const u16* __restrict__ Bt,
                    void* __restrict__ Cout, int mode, int kLo, int kHi,
                    u16* As, u16* Bs) {
  constexpr int K = 1024, N = 1024;
  const int t = threadIdx.x;
  const int lane = t & 63;
  const int quad = lane >> 4;
  const int l16 = lane & 15;
  const int wid = t >> 6;
  const int mBase = blockIdx.y * 128;
  const int nBase = blockIdx.x * 128;
  const int wM = (wid >> 1) * 64;
  const int wN = (wid & 1) * 64;
  const int cswz = l16 & 7;  // frag-read chunk xor

  f32x4 acc[4][4];
#pragma unroll
  for (int i = 0; i < 4; ++i)
#pragma unroll
    for (int j = 0; j < 4; ++j) acc[i][j] = (f32x4){0.f, 0.f, 0.f, 0.f};

  for (int kt = kLo; kt < kHi; ++kt) {
    const int kB = kt * 64;
    __syncthreads();  // protect LDS reuse from previous iteration's reads
#pragma unroll
    for (int i = 0; i < 4; ++i) {  // each tile 128x64 f16 = 1024 chunks / 256 thr
      const int ci = i * 256 + t;
      const int row = ci >> 3;                       // 8 chunks per 64-elem row
      const int col = (((ci & 7) ^ (row & 7)) << 3); // staging-side swizzle
      gl_lds16(A + (size_t)(mBase + row) * K + kB + col, As + ci * 8);
      gl_lds16(Bt + (size_t)(nBase + row) * K + kB + col, Bs + ci * 8);
    }
    __syncthreads();  // barrier drains vmcnt

#pragma unroll
    for (int kk = 0; kk < 2; ++kk) {
      const int ck = (((kk * 4 + quad) ^ cswz) << 3);
      half8 a[4], b[4];
#pragma unroll
      for (int mi = 0; mi < 4; ++mi)
        a[mi] = *(const half8*)(As + (wM + mi * 16 + l16) * 64 + ck);
#pragma unroll
      for (int ni = 0; ni < 4; ++ni)
        b[ni] = *(const half8*)(Bs + (wN + ni * 16 + l16) * 64 + ck);
#pragma unroll
      for (int mi = 0; mi < 4; ++mi)
#pragma unroll
        for (int ni = 0; ni < 4; ++ni)
          acc[mi][ni] = MFMA16(a[mi], b[ni], acc[mi][ni]);
    }
  }

  // epilogue. C/D layout: row = quad*4 + reg, col = lane&15 (m89/m91-verified)
#pragma unroll
  for (int mi = 0; mi < 4; ++mi) {
#pragma unroll
    for (int ni = 0; ni < 4; ++ni) {
#pragma unroll
      for (int r = 0; r < 4; ++r) {
        const int m = mBase + wM + mi * 16 + quad * 4 + r;
        const int n = nBase + wN + ni * 16 + l16;
        const float v = acc[mi][ni][r];
        if (mode == 0) {
          ((float*)Cout)[(size_t)m * N + n] = v;
        } else {
          ((u16*)Cout)[(size_t)m * N + n] = f2h_bits(v);
        }
      }
    }
  }
}

__global__ __launch_bounds__(256) void proj_qkv(
    const u16* __restrict__ qb, const u16* __restrict__ kb, const u16* __restrict__ vb,
    const u16* __restrict__ Wqt, const u16* __restrict__ Wkt, const u16* __restrict__ Wvt,
    u16* __restrict__ Qp, u16* __restrict__ Kp, u16* __restrict__ Vp) {
  __shared__ u16 As[128 * 64];
  __shared__ u16 Bs[128 * 64];
  const int z = blockIdx.z;
  const u16* A = z == 0 ? qb : (z == 1 ? kb : vb);
  const u16* Bt = z == 0 ? Wqt : (z == 1 ? Wkt : Wvt);
  void* C = z == 0 ? (void*)Qp : (z == 1 ? (void*)Kp : (void*)Vp);
  gemm_body(A, Bt, C, 1, 0, 16, As, Bs);
}

// split-K=2 into separate fp32 partial buffers (no atomics)
__global__ __launch_bounds__(256) void gemm_out(const u16* __restrict__ Ao,
                                                const u16* __restrict__ Wot,
                                                float* __restrict__ p0,
                                                float* __restrict__ p1) {
  __shared__ u16 As[128 * 64];
  __shared__ u16 Bs[128 * 64];
  const int z = blockIdx.z;
  gemm_body(Ao, Wot, z ? (void*)p1 : (void*)p0, 0, z * 8, z * 8 + 8, As, Bs);
}

// out = p0 + p1, float4
__global__ __launch_bounds__(256) void add2(const float* __restrict__ a,
                                            const float* __restrict__ b,
                                            float* __restrict__ o, int n) {
  int i = (blockIdx.x * 256 + threadIdx.x) * 4;
  if (i + 3 < n) {
    float4 x = *(const float4*)(a + i);
    const float4 y = *(const float4*)(b + i);
    x.x += y.x; x.y += y.y; x.z += y.z; x.w += y.w;
    *(float4*)(o + i) = x;
  }
}

// ---------------- flash attention + ALiBi, no-max exp2 softmax, SPLIT-K ----------------
// grid 1920 = 30 slots x 64 (b,qt); idx>>6 = slot rank (LPT: rank 0 = slot 29 =
// h15/seg3, longest). Each block does <=8 k-tiles of its (b,h,qt) window and
// writes unnormalized fp16 O_part (64x64) + fp32 l_part (64) to its slot.
// Linearity of the no-max softmax makes segments summable in the merge.
__global__ __launch_bounds__(128, 2) void flash_alibi(
    const u16* __restrict__ Qg, const u16* __restrict__ Kg,
    const u16* __restrict__ Vtg, u16* __restrict__ Opart,
    float* __restrict__ lpart) {
  constexpr int S = 2048, Dm = 1024, HD = 64;
  __shared__ u16 Qs[64 * 64];       // 8 KB
  __shared__ u16 Ks[2][64 * 64];    // 16 KB dbuf
  __shared__ u16 Vs[2][64 * 64];    // 16 KB dbuf  Vs[d][k]
  __shared__ u16 Ps[64 * 64];       // 8 KB  col-swizzled       (48 KB total)
  const int t = threadIdx.x, lane = t & 63, wid = t >> 6;  // wid 0..1
  const int quad = lane >> 4, l16 = lane & 15;
  const int idx = blockIdx.x;
  const int s = 29 - (idx >> 6);       // slot within (b,qt); 29 first (LPT)
  const int bq = idx & 63;             // b*32 + qt
  const int b = bq >> 5, qt = bq & 31;
  int h, seg, nseg;
  if      (s >= 26) { h = 15; seg = s - 26; nseg = 4; }
  else if (s >= 22) { h = 14; seg = s - 22; nseg = 4; }
  else if (s >= 18) { h = 13; seg = s - 18; nseg = 4; }
  else if (s >= 15) { h = 12; seg = s - 15; nseg = 3; }
  else if (s >= 13) { h = 11; seg = s - 13; nseg = 2; }
  else if (s >= 11) { h = 10; seg = s - 11; nseg = 2; }
  else if (s >= 9)  { h = 9;  seg = s - 9;  nseg = 2; }
  else              { h = s;  seg = 0;      nseg = 1; }
  const int qBase = qt * 64;
  const size_t qRow0 = (size_t)b * S + qBase;
  const float sl2 = __builtin_amdgcn_exp2f(-0.5f * (float)(h + 1)) * 1.44269504f;
  const float sc2 = 0.125f * 1.44269504f;  // (1/sqrt(64))*log2(e)
  const int Di = (int)(22.0f / sl2);
  const int ktLo = max(0, (qBase - Di) >> 6);
  const int ktHi = min(31, (qBase + 63 + Di) >> 6);
  const int W = ktHi - ktLo + 1;
  const int myLo = ktLo + (W * seg) / nseg;
  const int myHi = ktLo + (W * (seg + 1)) / nseg - 1;
  const size_t slotG = (size_t)bq * 30 + s;
  const int cswz = ((l16 & 7) << 3);  // frag-read chunk xor (x8 elems)
  const u16* Kgb = Kg + (size_t)b * S * Dm + h * HD;
  const u16* Vgb = Vtg + (size_t)(b * 16 + h) * HD * S;

  // stage Q tile once: 64 rows x 8 chunks = 512 chunks / 128 thr
#pragma unroll
  for (int i = 0; i < 4; ++i) {
    const int ci = i * 128 + t;
    const int row = ci >> 3, col = (((ci & 7) ^ (row & 7)) << 3);
    gl_lds16(Qg + (qRow0 + row) * Dm + h * HD + col, Qs + ci * 8);
  }
  // stage K/V of first tile into buffer 0
  if (myLo <= myHi) {
#pragma unroll
    for (int i = 0; i < 4; ++i) {
      const int ci = i * 128 + t;
      const int row = ci >> 3, col = (((ci & 7) ^ (row & 7)) << 3);
      gl_lds16(Kgb + (size_t)(myLo * 64 + row) * Dm + col, Ks[0] + ci * 8);
      gl_lds16(Vgb + (size_t)row * S + myLo * 64 + col, Vs[0] + ci * 8);
    }
  }

  // ALiBi row bias (constant over kt): bi[m][r] = sl2 * global_q_row
  float bi[2][4];
#pragma unroll
  for (int m = 0; m < 2; ++m)
#pragma unroll
    for (int r = 0; r < 4; ++r)
      bi[m][r] = sl2 * (float)(qBase + wid * 32 + m * 16 + quad * 4 + r);

  f32x4 acc_o[2][4];
#pragma unroll
  for (int m = 0; m < 2; ++m)
#pragma unroll
    for (int nd = 0; nd < 4; ++nd) acc_o[m][nd] = (f32x4){0.f, 0.f, 0.f, 0.f};
  float lrow[2][4] = {{0.f, 0.f, 0.f, 0.f}, {0.f, 0.f, 0.f, 0.f}};

  const int pRowBase = wid * 32;  // this wave's private 32-row P region
  int cur = 0;

  for (int kt = myLo; kt <= myHi; ++kt, cur ^= 1) {
    // fused drain+barrier: staging for buf[cur] (and Q, iter 0) done; also
    // orders prior-iter LDS reads of buf[cur^1] before its overwrite below.
    __asm__ volatile("s_waitcnt vmcnt(0) lgkmcnt(0)\n\ts_barrier" ::: "memory");

    // prefetch next K/V tile into the other buffer; compute below covers it
    if (kt < myHi) {
      const int kB2 = (kt + 1) * 64;
      u16* Kd = Ks[cur ^ 1];
      u16* Vd = Vs[cur ^ 1];
#pragma unroll
      for (int i = 0; i < 4; ++i) {
        const int ci = i * 128 + t;
        const int row = ci >> 3, col = (((ci & 7) ^ (row & 7)) << 3);
        gl_lds16(Kgb + (size_t)(kB2 + row) * Dm + col, Kd + ci * 8);
        gl_lds16(Vgb + (size_t)row * S + kB2 + col, Vd + ci * 8);
      }
    }

    const int kB = kt * 64;
    // S = Q K^T : per wave 32q x 64k
    f32x4 sc[2][4];
#pragma unroll
    for (int m = 0; m < 2; ++m)
#pragma unroll
      for (int ni = 0; ni < 4; ++ni) sc[m][ni] = (f32x4){0.f, 0.f, 0.f, 0.f};
#pragma unroll
    for (int ks = 0; ks < 2; ++ks) {
      const int ck = ((ks * 4 + quad) << 3) ^ cswz;
      const half8 a0 = *(const half8*)(Qs + (wid * 32 + l16) * HD + ck);
      const half8 a1 = *(const half8*)(Qs + (wid * 32 + 16 + l16) * HD + ck);
#pragma unroll
      for (int ni = 0; ni < 4; ++ni) {
        const half8 bk = *(const half8*)(Ks[cur] + (ni * 16 + l16) * HD + ck);
        sc[0][ni] = MFMA16(a0, bk, sc[0][ni]);
        sc[1][ni] = MFMA16(a1, bk, sc[1][ni]);
      }
    }

    // p = exp2(s*sc2 - |bi - bj|); per-lane l partials; write swizzled P
    float bj[4];
#pragma unroll
    for (int ni = 0; ni < 4; ++ni) bj[ni] = sl2 * (float)(kB + ni * 16 + l16);
#pragma unroll
    for (int m = 0; m < 2; ++m) {
#pragma unroll
      for (int r = 0; r < 4; ++r) {
        float rs = 0.f;
        const int prow = (pRowBase + m * 16 + quad * 4 + r) * 64;
#pragma unroll
        for (int ni = 0; ni < 4; ++ni) {
          const float d = fabsf(bi[m][r] - bj[ni]);
          const float p = __builtin_amdgcn_exp2f(sc[m][ni][r] * sc2 - d);
          rs += p;
          Ps[prow + ((ni * 16 + l16) ^ (quad << 4))] = f2h_bits(p);
        }
        lrow[m][r] += rs;
      }
    }
    // P region is per-wave: wave-local LDS drain is sufficient (no block barrier)
    __asm__ volatile("s_waitcnt lgkmcnt(0)" ::: "memory");

    // O += P V : P A-frags (swizzled, 16B-contiguous), V B-frags
#pragma unroll
    for (int ks = 0; ks < 2; ++ks) {
      const int pk = (ks * 32 + quad * 8) ^ ((l16 & 12) << 2);
      const int ck = ((ks * 4 + quad) << 3) ^ cswz;
      const half8 aP0 = *(const half8*)(Ps + (pRowBase + l16) * 64 + pk);
      const half8 aP1 = *(const half8*)(Ps + (pRowBase + 16 + l16) * 64 + pk);
#pragma unroll
      for (int nd = 0; nd < 4; ++nd) {
        const half8 bv = *(const half8*)(Vs[cur] + (nd * 16 + l16) * HD + ck);
        acc_o[0][nd] = MFMA16(aP0, bv, acc_o[0][nd]);
        acc_o[1][nd] = MFMA16(aP1, bv, acc_o[1][nd]);
      }
    }
  }

  // epilogue: reduce l across the 16 lanes sharing each row; write UNNORMALIZED
  // fp16 O_part + fp32 l_part to this block's slot.
#pragma unroll
  for (int m = 0; m < 2; ++m) {
#pragma unroll
    for (int r = 0; r < 4; ++r) {
      float l = lrow[m][r];
      l += __shfl_xor(l, 1);
      l += __shfl_xor(l, 2);
      l += __shfl_xor(l, 4);
      l += __shfl_xor(l, 8);
      const int rloc = wid * 32 + m * 16 + quad * 4 + r;
      if (l16 == 0) lpart[slotG * 64 + rloc] = l;
#pragma unroll
      for (int nd = 0; nd < 4; ++nd)
        Opart[slotG * 4096 + rloc * 64 + nd * 16 + l16] = f2h_bits(acc_o[m][nd][r]);
    }
  }
}

// ---- merge: Ao[b,q,h,d] = (sum_s O_part) / (sum_s l_part), fp16 out ----
// grid 1024: idx = bq*16 + h. 256 thr; thread t handles q=t>>2, d=(t&3)*16..+15
__global__ __launch_bounds__(256) void flash_merge(
    const u16* __restrict__ Opart, const float* __restrict__ lpart,
    u16* __restrict__ Ao) {
  const int idx = blockIdx.x;
  const int h = idx & 15, bq = idx >> 4;
  const int b = bq >> 5, qt = bq & 31;
  int base, nseg;
  if      (h == 15) { base = 26; nseg = 4; }
  else if (h == 14) { base = 22; nseg = 4; }
  else if (h == 13) { base = 18; nseg = 4; }
  else if (h == 12) { base = 15; nseg = 3; }
  else if (h == 11) { base = 13; nseg = 2; }
  else if (h == 10) { base = 11; nseg = 2; }
  else if (h == 9)  { base = 9;  nseg = 2; }
  else              { base = h;  nseg = 1; }
  const int t = threadIdx.x;
  const int q = t >> 2, dB = (t & 3) * 16;
  float acc[16];
#pragma unroll
  for (int j = 0; j < 16; ++j) acc[j] = 0.f;
  float l = 0.f;
  for (int sg = 0; sg < nseg; ++sg) {
    const size_t slotG = (size_t)bq * 30 + base + sg;
    l += lpart[slotG * 64 + q];
    const u16* p = Opart + slotG * 4096 + q * 64 + dB;
    const half8 v0 = *(const half8*)p;
    const half8 v1 = *(const half8*)(p + 8);
#pragma unroll
    for (int j = 0; j < 8; ++j) {
      acc[j] += (float)v0[j];
      acc[8 + j] += (float)v1[j];
    }
  }
  const float inv = 1.f / l;
  u16x8 o0, o1;
#pragma unroll
  for (int j = 0; j < 8; ++j) {
    o0[j] = f2h_bits(acc[j] * inv);
    o1[j] = f2h_bits(acc[8 + j] * inv);
  }
  u16* dst = Ao + ((size_t)(b * 2048 + qt * 64 + q)) * 1024 + h * 64 + dB;
  *(u16x8*)dst = o0;
  *(u16x8*)(dst + 8) = o1;
}

extern "C" void kernel_launch(void* const* d_in, const int* in_sizes, int n_in,
                              void* d_out, int out_size, void* d_ws, size_t ws_size,
                              hipStream_t stream) {
  const float* q  = (const float*)d_in[0];
  const float* k  = (const float*)d_in[1];
  const float* v  = (const float*)d_in[2];
  const float* Wq = (const float*)d_in[3];
  const float* Wk = (const float*)d_in[4];
  const float* Wv = (const float*)d_in[5];
  const float* Wo = (const float*)d_in[6];
  char* ws = (char*)d_ws;
  const size_t MB = 1ull << 20;
  // workspace map (64 MB). Regions are reused across phases:
  u16* qb  = (u16*)(ws + 0 * MB);    // 8 MB  q fp16           | then O_part (15.7MB w/ kb)
  u16* kb  = (u16*)(ws + 8 * MB);    // 8 MB
  u16* vb  = (u16*)(ws + 16 * MB);   // 8 MB  v fp16 -> Vt[b][h][64][2048]
  u16* Wqt = (u16*)(ws + 24 * MB);   // 2 MB  W^T fp16
  u16* Wkt = (u16*)(ws + 26 * MB);
  u16* Wvt = (u16*)(ws + 28 * MB);
  u16* Wot = (u16*)(ws + 30 * MB);
  u16* Qp  = (u16*)(ws + 32 * MB);   // 8 MB  Q proj           | then gemm_out p1 (w/ Kp)
  u16* Kp  = (u16*)(ws + 40 * MB);   // 8 MB
  u16* Vp  = (u16*)(ws + 48 * MB);   // 8 MB  V proj row-major | then l_part
  u16* Ao  = (u16*)(ws + 56 * MB);   // 8 MB  attention out [4096][1024]
  u16* Vt  = vb;
  u16*   Opart = (u16*)(ws + 0 * MB);    // 1920 slots x 8 KB = 15.7 MB (qb+kb, free)
  float* lpart = (float*)(ws + 48 * MB); // 1920 x 64 x 4 B (Vp, free after vtrans)
  float* p0 = (float*)(ws + 0 * MB);     // 16 MB (free after flash_merge)
  float* p1 = (float*)(ws + 32 * MB);    // 16 MB (Qp/Kp, free after flash)

  const int n = 2 * 2048 * 1024;  // == out_size (4M floats)
  cast3_h<<<dim3(n / 1024, 1, 3), 256, 0, stream>>>(q, k, v, qb, kb, vb, n);
  transpose4_h<<<dim3(32, 32, 4), 256, 0, stream>>>(Wq, Wk, Wv, Wo, Wqt, Wkt, Wvt, Wot);
  proj_qkv<<<dim3(8, 32, 3), 256, 0, stream>>>(qb, kb, vb, Wqt, Wkt, Wvt, Qp, Kp, Vp);
  vtrans<<<dim3(32, 32), 256, 0, stream>>>(Vp, Vt);
  flash_alibi<<<1920, 128, 0, stream>>>(Qp, Kp, Vt, Opart, lpart);
  flash_merge<<<1024, 256, 0, stream>>>(Opart, lpart, Ao);
  gemm_out<<<dim3(8, 32, 2), 256, 0, stream>>>(Ao, Wot, p0, p1);
  add2<<<4096, 256, 0, stream>>>(p0, p1, (float*)d_out, n);
}

// Round 9
// 236.416 us; speedup vs baseline: 1.1080x; 1.0403x over previous
//
#include <hip/hip_runtime.h>
#include <cstdint>
#include <cstddef>

// ALiBi MHA, MI355X/gfx950. fp16 MFMA (16x16x32) pipeline.
// R9 changes vs R8:
//  - flash: BQ=128, 256 thr / 4 waves, SINGLE-buffered K/V. Same 48KB LDS ->
//    still 3 blocks/CU but 12 waves/CU (was 6): occupancy ceiling 18.75%->37.5%.
//    K/V staging amortized over 2x Q-rows. Split-K table recomputed for the
//    wider windows (36 slots, all segments <=9 tiles, 1152 blocks).
//  - heads 0..6 (nseg==1) write normalized Ao directly; Opart/merge only h>=7.

typedef unsigned short u16;
typedef __attribute__((ext_vector_type(8))) _Float16 half8;
typedef __attribute__((ext_vector_type(8))) unsigned short u16x8;
typedef __attribute__((ext_vector_type(4))) float f32x4;

#define DEVI static __device__ __forceinline__
#define MFMA16(a, b, c) __builtin_amdgcn_mfma_f32_16x16x32_f16(a, b, c, 0, 0, 0)

DEVI u16 f2h_bits(float f) {
  _Float16 h = (_Float16)f;  // v_cvt_f16_f32, RNE
  union { _Float16 h; u16 u; } v; v.h = h;
  return v.u;
}

// async global->LDS, 16B per lane. LDS dest must be wave-uniform base + lane*16.
DEVI void gl_lds16(const u16* g, u16* l) {
  __builtin_amdgcn_global_load_lds(
      (const __attribute__((address_space(1))) void*)g,
      (__attribute__((address_space(3))) void*)l, 16, 0, 0);
}

// ---------------- cast fp32 -> fp16 bits, 4 elems/thread, z selects tensor ----------------
__global__ __launch_bounds__(256) void cast3_h(const float* __restrict__ in0,
                                               const float* __restrict__ in1,
                                               const float* __restrict__ in2,
                                               u16* __restrict__ o0,
                                               u16* __restrict__ o1,
                                               u16* __restrict__ o2, int n) {
  const float* in = blockIdx.z == 0 ? in0 : (blockIdx.z == 1 ? in1 : in2);
  u16* out = blockIdx.z == 0 ? o0 : (blockIdx.z == 1 ? o1 : o2);
  int i = (blockIdx.x * 256 + threadIdx.x) * 4;
  if (i + 3 < n) {
    const float4 v = *(const float4*)(in + i);
    ushort4 o;
    o.x = f2h_bits(v.x); o.y = f2h_bits(v.y); o.z = f2h_bits(v.z); o.w = f2h_bits(v.w);
    *(ushort4*)(out + i) = o;
  }
}

// ---------------- Wt[n][k] = (f16)W[k][n], 1024x1024, LDS-tiled, z selects W ----------------
__global__ __launch_bounds__(256) void transpose4_h(
    const float* __restrict__ W0, const float* __restrict__ W1,
    const float* __restrict__ W2, const float* __restrict__ W3,
    u16* __restrict__ T0, u16* __restrict__ T1, u16* __restrict__ T2,
    u16* __restrict__ T3) {
  const float* W = blockIdx.z == 0 ? W0 : (blockIdx.z == 1 ? W1 : (blockIdx.z == 2 ? W2 : W3));
  u16* Wt = blockIdx.z == 0 ? T0 : (blockIdx.z == 1 ? T1 : (blockIdx.z == 2 ? T2 : T3));
  __shared__ float tile[32][33];
  const int bx = blockIdx.x * 32;
  const int by = blockIdx.y * 32;
  const int x = threadIdx.x & 31;
  const int y0 = threadIdx.x >> 5;  // 0..7
#pragma unroll
  for (int i = y0; i < 32; i += 8)
    tile[i][x] = W[(size_t)(by + i) * 1024 + bx + x];
  __syncthreads();
#pragma unroll
  for (int i = y0; i < 32; i += 8)
    Wt[(size_t)(bx + i) * 1024 + by + x] = f2h_bits(tile[x][i]);
}

// ---- Vt[(b*16+h)*64+d][s] = Vp[b*2048+s][h*64+d], via 64x64 LDS tile ----
__global__ __launch_bounds__(256) void vtrans(const u16* __restrict__ Vp,
                                              u16* __restrict__ Vt) {
  __shared__ u16 tile[64][72];  // +8 pad breaks transpose-read bank alignment
  const int t = threadIdx.x;
  const int s0 = blockIdx.x * 64;
  const int bh = blockIdx.y;            // b*16 + h
  const int b = bh >> 4, h = bh & 15;
#pragma unroll
  for (int it = 0; it < 2; ++it) {
    const int ci = it * 256 + t;
    const int srow = ci >> 3, cc = (ci & 7) << 3;
    const u16x8 v = *(const u16x8*)(Vp + (size_t)(b * 2048 + s0 + srow) * 1024 + h * 64 + cc);
    *(u16x8*)(&tile[srow][cc]) = v;
  }
  __syncthreads();
#pragma unroll
  for (int it = 0; it < 2; ++it) {
    const int ci = it * 256 + t;
    const int drow = ci >> 3, cc = (ci & 7) << 3;
    u16x8 o;
#pragma unroll
    for (int j = 0; j < 8; ++j) o[j] = tile[cc + j][drow];
    *(u16x8*)(Vt + ((size_t)bh * 64 + drow) * 2048 + s0 + cc) = o;
  }
}

// ---------------- GEMM body, BK=64: C[128x128] tile of A[M][1024] x Bt[1024][1024]^T ----
// 64-elem LDS rows = 8 chunks of 8; staging-side chunk XOR (c ^ row&7) kills the
// 16-way frag-read conflict of the 128B row stride. mode 0: fp32; mode 1: f16.
DEVI void gemm_body(const u16* __restrict__ A, const u16* __restrict__ Bt,
                    void* __restrict__ Cout, int mode, int kLo, int kHi,
                    u16* As, u16* Bs) {
  constexpr int K = 1024, N = 1024;
  const int t = threadIdx.x;
  const int lane = t & 63;
  const int quad = lane >> 4;
  const int l16 = lane & 15;
  const int wid = t >> 6;
  const int mBase = blockIdx.y * 128;
  const int nBase = blockIdx.x * 128;
  const int wM = (wid >> 1) * 64;
  const int wN = (wid & 1) * 64;
  const int cswz = l16 & 7;  // frag-read chunk xor

  f32x4 acc[4][4];
#pragma unroll
  for (int i = 0; i < 4; ++i)
#pragma unroll
    for (int j = 0; j < 4; ++j) acc[i][j] = (f32x4){0.f, 0.f, 0.f, 0.f};

  for (int kt = kLo; kt < kHi; ++kt) {
    const int kB = kt * 64;
    __syncthreads();  // protect LDS reuse from previous iteration's reads
#pragma unroll
    for (int i = 0; i < 4; ++i) {  // each tile 128x64 f16 = 1024 chunks / 256 thr
      const int ci = i * 256 + t;
      const int row = ci >> 3;                       // 8 chunks per 64-elem row
      const int col = (((ci & 7) ^ (row & 7)) << 3); // staging-side swizzle
      gl_lds16(A + (size_t)(mBase + row) * K + kB + col, As + ci * 8);
      gl_lds16(Bt + (size_t)(nBase + row) * K + kB + col, Bs + ci * 8);
    }
    __syncthreads();  // barrier drains vmcnt

#pragma unroll
    for (int kk = 0; kk < 2; ++kk) {
      const int ck = (((kk * 4 + quad) ^ cswz) << 3);
      half8 a[4], b[4];
#pragma unroll
      for (int mi = 0; mi < 4; ++mi)
        a[mi] = *(const half8*)(As + (wM + mi * 16 + l16) * 64 + ck);
#pragma unroll
      for (int ni = 0; ni < 4; ++ni)
        b[ni] = *(const half8*)(Bs + (wN + ni * 16 + l16) * 64 + ck);
#pragma unroll
      for (int mi = 0; mi < 4; ++mi)
#pragma unroll
        for (int ni = 0; ni < 4; ++ni)
          acc[mi][ni] = MFMA16(a[mi], b[ni], acc[mi][ni]);
    }
  }

  // epilogue. C/D layout: row = quad*4 + reg, col = lane&15 (m89/m91-verified)
#pragma unroll
  for (int mi = 0; mi < 4; ++mi) {
#pragma unroll
    for (int ni = 0; ni < 4; ++ni) {
#pragma unroll
      for (int r = 0; r < 4; ++r) {
        const int m = mBase + wM + mi * 16 + quad * 4 + r;
        const int n = nBase + wN + ni * 16 + l16;
        const float v = acc[mi][ni][r];
        if (mode == 0) {
          ((float*)Cout)[(size_t)m * N + n] = v;
        } else {
          ((u16*)Cout)[(size_t)m * N + n] = f2h_bits(v);
        }
      }
    }
  }
}

__global__ __launch_bounds__(256) void proj_qkv(
    const u16* __restrict__ qb, const u16* __restrict__ kb, const u16* __restrict__ vb,
    const u16* __restrict__ Wqt, const u16* __restrict__ Wkt, const u16* __restrict__ Wvt,
    u16* __restrict__ Qp, u16* __restrict__ Kp, u16* __restrict__ Vp) {
  __shared__ u16 As[128 * 64];
  __shared__ u16 Bs[128 * 64];
  const int z = blockIdx.z;
  const u16* A = z == 0 ? qb : (z == 1 ? kb : vb);
  const u16* Bt = z == 0 ? Wqt : (z == 1 ? Wkt : Wvt);
  void* C = z == 0 ? (void*)Qp : (z == 1 ? (void*)Kp : (void*)Vp);
  gemm_body(A, Bt, C, 1, 0, 16, As, Bs);
}

// split-K=2 into separate fp32 partial buffers (no atomics)
__global__ __launch_bounds__(256) void gemm_out(const u16* __restrict__ Ao,
                                                const u16* __restrict__ Wot,
                                                float* __restrict__ p0,
                                                float* __restrict__ p1) {
  __shared__ u16 As[128 * 64];
  __shared__ u16 Bs[128 * 64];
  const int z = blockIdx.z;
  gemm_body(Ao, Wot, z ? (void*)p1 : (void*)p0, 0, z * 8, z * 8 + 8, As, Bs);
}

// out = p0 + p1, float4
__global__ __launch_bounds__(256) void add2(const float* __restrict__ a,
                                            const float* __restrict__ b,
                                            float* __restrict__ o, int n) {
  int i = (blockIdx.x * 256 + threadIdx.x) * 4;
  if (i + 3 < n) {
    float4 x = *(const float4*)(a + i);
    const float4 y = *(const float4*)(b + i);
    x.x += y.x; x.y += y.y; x.z += y.z; x.w += y.w;
    *(float4*)(o + i) = x;
  }
}

// ---------------- flash attention + ALiBi, no-max exp2 softmax, SPLIT-K ----------------
// BQ=128, 256 thr = 4 waves x 32 q-rows, K-tile 64, single-buffered K/V.
// grid 1152 = 36 slots x 32 (b,qt); rank = idx>>5, s = 35-rank (h15 first).
// Slot table: s<7 -> h=s nseg=1 (writes Ao directly, normalized);
// s 7-8:h7/2, 9-10:h8/2, 11-12:h9/2, 13-15:h10/3, 16+:h11..15 nseg=4.
// All segments <=9 k-tiles. ALiBi skip: tile dropped when sl2*dist > 22.
__global__ __launch_bounds__(256, 3) void flash_alibi(
    const u16* __restrict__ Qg, const u16* __restrict__ Kg,
    const u16* __restrict__ Vtg, u16* __restrict__ Ao,
    u16* __restrict__ Opart, float* __restrict__ lpart) {
  constexpr int S = 2048, Dm = 1024, HD = 64;
  __shared__ u16 Qs[128 * 64];  // 16 KB
  __shared__ u16 Ks[64 * 64];   //  8 KB
  __shared__ u16 Vs[64 * 64];   //  8 KB  Vs[d][k]
  __shared__ u16 Ps[128 * 64];  // 16 KB  col-swizzled        (48 KB total)
  const int t = threadIdx.x, lane = t & 63, wid = t >> 6;  // wid 0..3
  const int quad = lane >> 4, l16 = lane & 15;
  const int idx = blockIdx.x;
  const int s = 35 - (idx >> 5);       // slot; 35 (h15) dispatched first
  const int bq = idx & 31;             // b*16 + qt
  const int b = bq >> 4, qt = bq & 15;
  int h, seg, nseg;
  if      (s >= 32) { h = 15; seg = s - 32; nseg = 4; }
  else if (s >= 28) { h = 14; seg = s - 28; nseg = 4; }
  else if (s >= 24) { h = 13; seg = s - 24; nseg = 4; }
  else if (s >= 20) { h = 12; seg = s - 20; nseg = 4; }
  else if (s >= 16) { h = 11; seg = s - 16; nseg = 4; }
  else if (s >= 13) { h = 10; seg = s - 13; nseg = 3; }
  else if (s >= 11) { h = 9;  seg = s - 11; nseg = 2; }
  else if (s >= 9)  { h = 8;  seg = s - 9;  nseg = 2; }
  else if (s >= 7)  { h = 7;  seg = s - 7;  nseg = 2; }
  else              { h = s;  seg = 0;      nseg = 1; }
  const int qBase = qt * 128;
  const size_t qRow0 = (size_t)b * S + qBase;
  const float sl2 = __builtin_amdgcn_exp2f(-0.5f * (float)(h + 1)) * 1.44269504f;
  const float sc2 = 0.125f * 1.44269504f;  // (1/sqrt(64))*log2(e)
  const int Di = (int)(22.0f / sl2);
  const int ktLo = max(0, (qBase - Di) >> 6);
  const int ktHi = min(31, (qBase + 127 + Di) >> 6);
  const int W = ktHi - ktLo + 1;
  const int myLo = ktLo + (W * seg) / nseg;
  const int myHi = ktLo + (W * (seg + 1)) / nseg - 1;
  const int cswz = ((l16 & 7) << 3);  // frag-read chunk xor (x8 elems)
  const u16* Kgb = Kg + (size_t)b * S * Dm + h * HD;
  const u16* Vgb = Vtg + (size_t)(b * 16 + h) * HD * S;

  // stage Q tile once: 128 rows x 8 chunks = 1024 chunks / 256 thr
#pragma unroll
  for (int i = 0; i < 4; ++i) {
    const int ci = i * 256 + t;
    const int row = ci >> 3, col = (((ci & 7) ^ (row & 7)) << 3);
    gl_lds16(Qg + (qRow0 + row) * Dm + h * HD + col, Qs + ci * 8);
  }

  // ALiBi row bias (constant over kt): rows qBase + wid*32 + m*16 + quad*4 + r
  float bi[2][4];
#pragma unroll
  for (int m = 0; m < 2; ++m)
#pragma unroll
    for (int r = 0; r < 4; ++r)
      bi[m][r] = sl2 * (float)(qBase + wid * 32 + m * 16 + quad * 4 + r);

  f32x4 acc_o[2][4];
#pragma unroll
  for (int m = 0; m < 2; ++m)
#pragma unroll
    for (int nd = 0; nd < 4; ++nd) acc_o[m][nd] = (f32x4){0.f, 0.f, 0.f, 0.f};
  float lrow[2][4] = {{0.f, 0.f, 0.f, 0.f}, {0.f, 0.f, 0.f, 0.f}};

  const int pRowBase = wid * 32;  // this wave's private 32-row P region

  for (int kt = myLo; kt <= myHi; ++kt) {
    __syncthreads();  // prev-iter Ks/Vs reads done (Q staging drained too, iter 0)
#pragma unroll
    for (int i = 0; i < 2; ++i) {  // K and V tiles: 512 chunks each / 256 thr
      const int ci = i * 256 + t;
      const int row = ci >> 3, col = (((ci & 7) ^ (row & 7)) << 3);
      gl_lds16(Kgb + (size_t)(kt * 64 + row) * Dm + col, Ks + ci * 8);
      gl_lds16(Vgb + (size_t)row * S + kt * 64 + col, Vs + ci * 8);
    }
    __syncthreads();  // barrier drains vmcnt

    const int kB = kt * 64;
    // S = Q K^T : per wave 32q x 64k
    f32x4 sc[2][4];
#pragma unroll
    for (int m = 0; m < 2; ++m)
#pragma unroll
      for (int ni = 0; ni < 4; ++ni) sc[m][ni] = (f32x4){0.f, 0.f, 0.f, 0.f};
#pragma unroll
    for (int ks = 0; ks < 2; ++ks) {
      const int ck = ((ks * 4 + quad) << 3) ^ cswz;
      const half8 a0 = *(const half8*)(Qs + (wid * 32 + l16) * HD + ck);
      const half8 a1 = *(const half8*)(Qs + (wid * 32 + 16 + l16) * HD + ck);
#pragma unroll
      for (int ni = 0; ni < 4; ++ni) {
        const half8 bk = *(const half8*)(Ks + (ni * 16 + l16) * HD + ck);
        sc[0][ni] = MFMA16(a0, bk, sc[0][ni]);
        sc[1][ni] = MFMA16(a1, bk, sc[1][ni]);
      }
    }

    // p = exp2(s*sc2 - |bi - bj|); per-lane l partials; write swizzled P
    float bj[4];
#pragma unroll
    for (int ni = 0; ni < 4; ++ni) bj[ni] = sl2 * (float)(kB + ni * 16 + l16);
#pragma unroll
    for (int m = 0; m < 2; ++m) {
#pragma unroll
      for (int r = 0; r < 4; ++r) {
        float rs = 0.f;
        const int prow = (pRowBase + m * 16 + quad * 4 + r) * 64;
#pragma unroll
        for (int ni = 0; ni < 4; ++ni) {
          const float d = fabsf(bi[m][r] - bj[ni]);
          const float p = __builtin_amdgcn_exp2f(sc[m][ni][r] * sc2 - d);
          rs += p;
          Ps[prow + ((ni * 16 + l16) ^ (quad << 4))] = f2h_bits(p);
        }
        lrow[m][r] += rs;
      }
    }
    // P region is per-wave: wave-local LDS drain is sufficient (no block barrier)
    __asm__ volatile("s_waitcnt lgkmcnt(0)" ::: "memory");

    // O += P V : P A-frags (swizzled, 16B-contiguous), V B-frags
#pragma unroll
    for (int ks = 0; ks < 2; ++ks) {
      const int pk = (ks * 32 + quad * 8) ^ ((l16 & 12) << 2);
      const int ck = ((ks * 4 + quad) << 3) ^ cswz;
      const half8 aP0 = *(const half8*)(Ps + (pRowBase + l16) * 64 + pk);
      const half8 aP1 = *(const half8*)(Ps + (pRowBase + 16 + l16) * 64 + pk);
#pragma unroll
      for (int nd = 0; nd < 4; ++nd) {
        const half8 bv = *(const half8*)(Vs + (nd * 16 + l16) * HD + ck);
        acc_o[0][nd] = MFMA16(aP0, bv, acc_o[0][nd]);
        acc_o[1][nd] = MFMA16(aP1, bv, acc_o[1][nd]);
      }
    }
  }

  // epilogue: reduce l across the 16 lanes sharing each row.
  // nseg==1 (h<=6): write normalized fp16 straight to Ao.
  // else: write unnormalized fp16 O_part + fp32 l_part to slot (s-7).
  const size_t slotG = (size_t)bq * 29 + (s - 7);  // only used when nseg>1
#pragma unroll
  for (int m = 0; m < 2; ++m) {
#pragma unroll
    for (int r = 0; r < 4; ++r) {
      float l = lrow[m][r];
      l += __shfl_xor(l, 1);
      l += __shfl_xor(l, 2);
      l += __shfl_xor(l, 4);
      l += __shfl_xor(l, 8);
      const int rloc = wid * 32 + m * 16 + quad * 4 + r;
      if (nseg == 1) {
        const float inv = 1.f / l;
#pragma unroll
        for (int nd = 0; nd < 4; ++nd)
          Ao[(qRow0 + rloc) * Dm + h * HD + nd * 16 + l16] =
              f2h_bits(acc_o[m][nd][r] * inv);
      } else {
        if (l16 == 0) lpart[slotG * 128 + rloc] = l;
#pragma unroll
        for (int nd = 0; nd < 4; ++nd)
          Opart[slotG * 8192 + rloc * 64 + nd * 16 + l16] = f2h_bits(acc_o[m][nd][r]);
      }
    }
  }
}

// ---- merge (h>=7 only): Ao = (sum_s O_part) / (sum_s l_part), fp16 out ----
// grid 288 = 32 bq x 9 heads. thread t: q = t>>1 (0..127), d-half = (t&1)*32.
__global__ __launch_bounds__(256) void flash_merge(
    const u16* __restrict__ Opart, const float* __restrict__ lpart,
    u16* __restrict__ Ao) {
  const int idx = blockIdx.x;
  const int bq = idx / 9, hm = idx - bq * 9;
  const int h = 7 + hm;
  const int b = bq >> 4, qt = bq & 15;
  int base, nseg;
  if      (h == 15) { base = 32; nseg = 4; }
  else if (h == 14) { base = 28; nseg = 4; }
  else if (h == 13) { base = 24; nseg = 4; }
  else if (h == 12) { base = 20; nseg = 4; }
  else if (h == 11) { base = 16; nseg = 4; }
  else if (h == 10) { base = 13; nseg = 3; }
  else if (h == 9)  { base = 11; nseg = 2; }
  else if (h == 8)  { base = 9;  nseg = 2; }
  else              { base = 7;  nseg = 2; }
  const int t = threadIdx.x;
  const int q = t >> 1, d0 = (t & 1) * 32;
  float acc[32];
#pragma unroll
  for (int j = 0; j < 32; ++j) acc[j] = 0.f;
  float l = 0.f;
  for (int sg = 0; sg < nseg; ++sg) {
    const size_t slotG = (size_t)bq * 29 + (base - 7) + sg;
    l += lpart[slotG * 128 + q];
    const u16* p = Opart + slotG * 8192 + q * 64 + d0;
#pragma unroll
    for (int c = 0; c < 4; ++c) {
      const half8 v = *(const half8*)(p + c * 8);
#pragma unroll
      for (int j = 0; j < 8; ++j) acc[c * 8 + j] += (float)v[j];
    }
  }
  const float inv = 1.f / l;
  u16* dst = Ao + ((size_t)(b * 2048 + qt * 128 + q)) * 1024 + h * 64 + d0;
#pragma unroll
  for (int c = 0; c < 4; ++c) {
    u16x8 o;
#pragma unroll
    for (int j = 0; j < 8; ++j) o[j] = f2h_bits(acc[c * 8 + j] * inv);
    *(u16x8*)(dst + c * 8) = o;
  }
}

extern "C" void kernel_launch(void* const* d_in, const int* in_sizes, int n_in,
                              void* d_out, int out_size, void* d_ws, size_t ws_size,
                              hipStream_t stream) {
  const float* q  = (const float*)d_in[0];
  const float* k  = (const float*)d_in[1];
  const float* v  = (const float*)d_in[2];
  const float* Wq = (const float*)d_in[3];
  const float* Wk = (const float*)d_in[4];
  const float* Wv = (const float*)d_in[5];
  const float* Wo = (const float*)d_in[6];
  char* ws = (char*)d_ws;
  const size_t MB = 1ull << 20;
  // workspace map (64 MB). Regions reused across phases:
  u16* qb  = (u16*)(ws + 0 * MB);    // 8 MB  q fp16          | then Opart (14.5MB w/ kb)
  u16* kb  = (u16*)(ws + 8 * MB);    // 8 MB                  | then p0 after merge
  u16* vb  = (u16*)(ws + 16 * MB);   // 8 MB  v fp16 -> Vt[b][h][64][2048]
  u16* Wqt = (u16*)(ws + 24 * MB);   // 2 MB  W^T fp16
  u16* Wkt = (u16*)(ws + 26 * MB);
  u16* Wvt = (u16*)(ws + 28 * MB);
  u16* Wot = (u16*)(ws + 30 * MB);
  u16* Qp  = (u16*)(ws + 32 * MB);   // 8 MB  Q proj          | then p1 after flash
  u16* Kp  = (u16*)(ws + 40 * MB);   // 8 MB
  u16* Vp  = (u16*)(ws + 48 * MB);   // 8 MB  V row-major     | then lpart after vtrans
  u16* Ao  = (u16*)(ws + 56 * MB);   // 8 MB  attention out [4096][1024] fp16
  u16* Vt  = vb;
  u16*   Opart = (u16*)(ws + 0 * MB);    // 928 slots x 16 KB = 14.5 MB
  float* lpart = (float*)(ws + 48 * MB); // 928 x 128 x 4 B = 475 KB
  float* p0 = (float*)(ws + 0 * MB);     // 16 MB (Opart dead after merge)
  float* p1 = (float*)(ws + 32 * MB);    // 16 MB (Qp/Kp dead after flash)

  const int n = 2 * 2048 * 1024;  // == out_size (4M floats)
  cast3_h<<<dim3(n / 1024, 1, 3), 256, 0, stream>>>(q, k, v, qb, kb, vb, n);
  transpose4_h<<<dim3(32, 32, 4), 256, 0, stream>>>(Wq, Wk, Wv, Wo, Wqt, Wkt, Wvt, Wot);
  proj_qkv<<<dim3(8, 32, 3), 256, 0, stream>>>(qb, kb, vb, Wqt, Wkt, Wvt, Qp, Kp, Vp);
  vtrans<<<dim3(32, 32), 256, 0, stream>>>(Vp, Vt);
  flash_alibi<<<1152, 256, 0, stream>>>(Qp, Kp, Vt, Ao, Opart, lpart);
  flash_merge<<<288, 256, 0, stream>>>(Opart, lpart, Ao);
  gemm_out<<<dim3(8, 32, 2), 256, 0, stream>>>(Ao, Wot, p0, p1);
  add2<<<4096, 256, 0, stream>>>(p0, p1, (float*)d_out, n);
}